// Round 1
// 324.392 us; speedup vs baseline: 1.1076x; 1.1076x over previous
//
#include <hip/hip_runtime.h>
#include <hip/hip_bf16.h>
#include <hip/hip_fp16.h>

#define EMBED 640
#define CROSS 768
#define NH 8
#define HEAD 80
#define BATCH 8
#define SEQT 4096
#define SEQS 77
#define MROWS (BATCH * SEQT)

typedef _Float16 half8 __attribute__((ext_vector_type(8)));
typedef float floatx4 __attribute__((ext_vector_type(4)));

__device__ __forceinline__ void lds_load16(const void* g, void* l) {
    __builtin_amdgcn_global_load_lds(
        (const __attribute__((address_space(1))) void*)g,
        (__attribute__((address_space(3))) void*)l, 16, 0, 0);
}

// ---------------------------------------------------------------------------
// fp32 -> f16 cast, 8 elems/thread (n divisible by 2048*... exact grids used).
// ---------------------------------------------------------------------------
__global__ __launch_bounds__(256) void cvt_f32_f16(
    const float* __restrict__ in, _Float16* __restrict__ out)
{
    size_t i = ((size_t)blockIdx.x * 256 + threadIdx.x) * 8;
    float4 a = *(const float4*)&in[i];
    float4 b = *(const float4*)&in[i + 4];
    half8 h;
    h[0] = (_Float16)a.x; h[1] = (_Float16)a.y;
    h[2] = (_Float16)a.z; h[3] = (_Float16)a.w;
    h[4] = (_Float16)b.x; h[5] = (_Float16)b.y;
    h[6] = (_Float16)b.z; h[7] = (_Float16)b.w;
    *(half8*)&out[i] = h;
}

// y [616*768] fp32 -> yh [640][768] f16, rows 616..639 zeroed.
__global__ __launch_bounds__(256) void cvt_y_f16(
    const float* __restrict__ y, _Float16* __restrict__ yh)
{
    size_t i = ((size_t)blockIdx.x * 256 + threadIdx.x) * 8;  // < 640*768
    half8 h = {};
    if (i < (size_t)BATCH * SEQS * CROSS) {
        float4 a = *(const float4*)&y[i];
        float4 b = *(const float4*)&y[i + 4];
        h[0] = (_Float16)a.x; h[1] = (_Float16)a.y;
        h[2] = (_Float16)a.z; h[3] = (_Float16)a.w;
        h[4] = (_Float16)b.x; h[5] = (_Float16)b.y;
        h[6] = (_Float16)b.z; h[7] = (_Float16)b.w;
    }
    *(half8*)&yh[i] = h;
}

__global__ __launch_bounds__(256) void zero_f16(_Float16* __restrict__ p, size_t n8)
{
    size_t i = (size_t)blockIdx.x * 256 + threadIdx.x;
    if (i < n8) *(half8*)&p[i * 8] = (half8){};
}

// ---------------------------------------------------------------------------
// W [K,N] fp32  ->  Wt [N,K] f16   (tiled transpose, 32x32)
// ---------------------------------------------------------------------------
__global__ __launch_bounds__(256) void transpose_cvt(
    const float* __restrict__ W, _Float16* __restrict__ Wt, int K, int N)
{
    __shared__ float t[32][33];
    const int k0 = blockIdx.y * 32, n0 = blockIdx.x * 32;
    for (int r = threadIdx.y; r < 32; r += 8)
        t[r][threadIdx.x] = W[(size_t)(k0 + r) * N + n0 + threadIdx.x];
    __syncthreads();
    for (int r = threadIdx.y; r < 32; r += 8)
        Wt[(size_t)(n0 + r) * K + k0 + threadIdx.x] = (_Float16)t[threadIdx.x][r];
}

// ---------------------------------------------------------------------------
// f16 MFMA GEMM (m97 structure): C = A[M,K] @ Bt[N,K]^T + bias, then *scale.
// HALF_OUT: write f16 (for Q, scale=1/sqrt(80) folded) else fp32.
// ---------------------------------------------------------------------------
template <bool HALF_OUT>
__global__ __launch_bounds__(256) void gemm_f16(
    const _Float16* __restrict__ A,   // [M,K] f16
    const _Float16* __restrict__ Bt,  // [N,K] f16
    const float* __restrict__ bias,
    void* __restrict__ Cout, int M, int N, int K, float scale)
{
    __shared__ _Float16 As[128 * 32];
    __shared__ _Float16 Bs[128 * 32];

    const int tid  = threadIdx.x;
    const int wave = tid >> 6;
    const int lane = tid & 63;
    const int quad = lane >> 4;
    const int l16  = lane & 15;
    const int m0 = blockIdx.y * 128, n0 = blockIdx.x * 128;
    const int wm = (wave >> 1) * 64, wn = (wave & 1) * 64;

    const int row = tid >> 2;
    const int kch = (tid & 3) * 8;

    floatx4 acc[4][4] = {};

    for (int k0 = 0; k0 < K; k0 += 32) {
        const _Float16* ga0 = &A [(size_t)(m0 + row)      * K + k0 + kch];
        const _Float16* ga1 = &A [(size_t)(m0 + 64 + row) * K + k0 + kch];
        const _Float16* gb0 = &Bt[(size_t)(n0 + row)      * K + k0 + kch];
        const _Float16* gb1 = &Bt[(size_t)(n0 + 64 + row) * K + k0 + kch];
        lds_load16(ga0, &As[wave * 512]);
        lds_load16(ga1, &As[2048 + wave * 512]);
        lds_load16(gb0, &Bs[wave * 512]);
        lds_load16(gb1, &Bs[2048 + wave * 512]);
        __syncthreads();

        half8 a[4], b[4];
        #pragma unroll
        for (int i = 0; i < 4; ++i)
            a[i] = *(const half8*)&As[(wm + i * 16 + l16) * 32 + quad * 8];
        #pragma unroll
        for (int j = 0; j < 4; ++j)
            b[j] = *(const half8*)&Bs[(wn + j * 16 + l16) * 32 + quad * 8];
        #pragma unroll
        for (int i = 0; i < 4; ++i)
            #pragma unroll
            for (int j = 0; j < 4; ++j)
                acc[i][j] = __builtin_amdgcn_mfma_f32_16x16x32_f16(
                    a[i], b[j], acc[i][j], 0, 0, 0);
        __syncthreads();
    }

    float bcol[4];
    #pragma unroll
    for (int j = 0; j < 4; ++j) bcol[j] = bias[n0 + wn + j * 16 + l16];
    #pragma unroll
    for (int i = 0; i < 4; ++i)
        #pragma unroll
        for (int r = 0; r < 4; ++r) {
            const int m = m0 + wm + i * 16 + quad * 4 + r;
            #pragma unroll
            for (int j = 0; j < 4; ++j) {
                float v = (acc[i][j][r] + bcol[j]) * scale;
                const size_t off = (size_t)m * N + n0 + wn + j * 16 + l16;
                if (HALF_OUT) ((_Float16*)Cout)[off] = (_Float16)v;
                else          ((float*)Cout)[off] = v;
            }
        }
}

// ---------------------------------------------------------------------------
// K/V projection via MFMA. 64x64 tiles, 4 waves (wave w = cols w*16..w*16+15).
// A = yh [640][768] f16 (rows 616+ zero), B = Wkt/Wvt [640][768] f16.
// Epilogue scatters f16 into attention layouts:
//   kh [bh][s(77)][d(80)], vth[bh][d(80)][s(80, pads pre-zeroed)]
// ---------------------------------------------------------------------------
__global__ __launch_bounds__(256) void kv_gemm(
    const _Float16* __restrict__ yh,
    const _Float16* __restrict__ Wkt, const _Float16* __restrict__ Wvt,
    const float* __restrict__ bk, const float* __restrict__ bv,
    _Float16* __restrict__ kh, _Float16* __restrict__ vth)
{
    __shared__ _Float16 As[64 * 32];
    __shared__ _Float16 Bs[64 * 32];

    const int tid = threadIdx.x;
    const int wave = tid >> 6, lane = tid & 63;
    const int quad = lane >> 4, l16 = lane & 15;
    const int m0 = blockIdx.y * 64, n0 = blockIdx.x * 64;
    const bool isV = blockIdx.z != 0;
    const _Float16* Bt = isV ? Wvt : Wkt;
    const float* bias  = isV ? bv : bk;

    const int row = tid >> 2;        // 0..63
    const int kch = (tid & 3) * 8;   // k chunk (8 f16 = 16 B)

    floatx4 acc[4] = {};

    for (int k0 = 0; k0 < CROSS; k0 += 32) {
        lds_load16(&yh[(size_t)(m0 + row) * CROSS + k0 + kch], &As[wave * 512]);
        lds_load16(&Bt[(size_t)(n0 + row) * CROSS + k0 + kch], &Bs[wave * 512]);
        __syncthreads();
        half8 b = *(const half8*)&Bs[(wave * 16 + l16) * 32 + quad * 8];
        #pragma unroll
        for (int i = 0; i < 4; ++i) {
            half8 a = *(const half8*)&As[(i * 16 + l16) * 32 + quad * 8];
            acc[i] = __builtin_amdgcn_mfma_f32_16x16x32_f16(a, b, acc[i], 0, 0, 0);
        }
        __syncthreads();
    }

    const int n = n0 + wave * 16 + l16;     // 0..639
    const int h = n / HEAD, d = n % HEAD;
    const float bb = bias[n];
    #pragma unroll
    for (int i = 0; i < 4; ++i)
        #pragma unroll
        for (int r = 0; r < 4; ++r) {
            const int m = m0 + i * 16 + quad * 4 + r;
            if (m >= BATCH * SEQS) continue;
            const int b_ = m / SEQS, s = m % SEQS;
            const int bh = b_ * NH + h;
            const float v = acc[i][r] + bb;
            if (isV) vth[(size_t)bh * (HEAD * 80) + d * 80 + s] = (_Float16)v;
            else     kh [(size_t)bh * (SEQS * HEAD) + s * HEAD + d] = (_Float16)v;
        }
}

// ---------------------------------------------------------------------------
// MFMA attention v2: persistent K/V per block.
// Grid (16, 64): block = one (b,h) x 256 q-rows (4 tiles of 64).
// - K/V staged to LDS ONCE per block (amortized over 4 tiles).
// - Q fragments loaded straight from global (no Qs LDS; rows indexed by l16,
//   k-chunks by quad); next tile's Q prefetched during current PV.
// - LDS stride 88 f16 (= 176 B, 16B-aligned). k-range 80..95 of the MFMA
//   fragments: A-side (Q, P) register-zeroed for quad>=2; B-side pad cols
//   80..87 zeroed at staging (NaN safety), cols 88..95 read into next row's
//   finite data (harmless: A is zero there).
// LDS total 39440 B -> 4 blocks/CU (vs 59904 -> 2 before).
// ---------------------------------------------------------------------------
__global__ __launch_bounds__(256, 4) void attn_mfma(
    const _Float16* __restrict__ qh,   // [M][EMBED], 1/sqrt(80) pre-folded
    const _Float16* __restrict__ kh,   // [64][77][80]
    const _Float16* __restrict__ vth,  // [64][80][80]
    _Float16* __restrict__ oh)         // [M][EMBED]
{
    constexpr int LS = 88;             // f16 LDS row stride (80 data + 8 pad)
    __shared__ _Float16 lds[(80 + 80 + 64) * LS + 8];
    _Float16* Ks = lds;                // [80][LS]  rows 77..79 zeroed
    _Float16* Vt = lds + 80 * LS;      // [80][LS]
    _Float16* Ps = lds + 160 * LS;     // [64][LS]

    const int tid = threadIdx.x;
    const int wave = tid >> 6, lane = tid & 63;
    const int quad = lane >> 4, l16 = lane & 15;
    const int bh = blockIdx.y;
    const int b = bh >> 3, h = bh & 7;
    const size_t row0 = (size_t)b * SEQT + (size_t)blockIdx.x * 256;
    const half8 hz = {};

    // Q base for this lane's A-fragment row (A row index = l16)
    const _Float16* qp = qh + (row0 + wave * 16 + l16) * EMBED + h * HEAD;

    // tile 0 Q fragments (overlap with staging below)
    half8 qa0 = *(const half8*)&qp[quad * 8];
    half8 qa1 = *(const half8*)&qp[32 + quad * 8];
    half8 qa2 = (quad < 2) ? *(const half8*)&qp[64 + quad * 8] : hz;

    // stage K (rows >= 77 and pad chunk zeroed)
    for (int idx = tid; idx < 80 * 11; idx += 256) {
        const int s = idx / 11, c = idx % 11;
        half8 v = hz;
        if (s < SEQS && c < 10)
            v = *(const half8*)&kh[(size_t)bh * (SEQS * HEAD) + s * HEAD + c * 8];
        *(half8*)&Ks[s * LS + c * 8] = v;
    }
    // stage V^T (pad chunk zeroed; cols s>=77 are zero in global)
    for (int idx = tid; idx < 80 * 11; idx += 256) {
        const int d = idx / 11, c = idx % 11;
        half8 v = hz;
        if (c < 10)
            v = *(const half8*)&vth[(size_t)bh * (HEAD * 80) + d * 80 + c * 8];
        *(half8*)&Vt[d * LS + c * 8] = v;
    }
    __syncthreads();

    for (int t = 0; t < 4; ++t) {
        // ---- QK^T ----
        floatx4 accs[5] = {};
        #pragma unroll
        for (int st = 0; st < 5; ++st) {
            const _Float16* kr = &Ks[(st * 16 + l16) * LS];
            half8 b0 = *(const half8*)&kr[quad * 8];
            half8 b1 = *(const half8*)&kr[32 + quad * 8];
            half8 b2 = *(const half8*)&kr[64 + quad * 8];
            accs[st] = __builtin_amdgcn_mfma_f32_16x16x32_f16(qa0, b0, accs[st], 0, 0, 0);
            accs[st] = __builtin_amdgcn_mfma_f32_16x16x32_f16(qa1, b1, accs[st], 0, 0, 0);
            accs[st] = __builtin_amdgcn_mfma_f32_16x16x32_f16(qa2, b2, accs[st], 0, 0, 0);
        }
        if (l16 >= 13) {
            accs[4][0] = -1e30f; accs[4][1] = -1e30f;
            accs[4][2] = -1e30f; accs[4][3] = -1e30f;
        }

        // ---- softmax (row = wave*16 + quad*4 + r, cols st*16 + l16) ----
        float recip[4];
        #pragma unroll
        for (int r = 0; r < 4; ++r) {
            float m = accs[0][r];
            #pragma unroll
            for (int st = 1; st < 5; ++st) m = fmaxf(m, accs[st][r]);
            m = fmaxf(m, __shfl_xor(m, 1));
            m = fmaxf(m, __shfl_xor(m, 2));
            m = fmaxf(m, __shfl_xor(m, 4));
            m = fmaxf(m, __shfl_xor(m, 8));
            float l = 0.f;
            const int row = wave * 16 + quad * 4 + r;
            #pragma unroll
            for (int st = 0; st < 5; ++st) {
                float e = __expf(accs[st][r] - m);
                l += e;
                Ps[row * LS + st * 16 + l16] = (_Float16)e;
            }
            l += __shfl_xor(l, 1);
            l += __shfl_xor(l, 2);
            l += __shfl_xor(l, 4);
            l += __shfl_xor(l, 8);
            recip[r] = 1.0f / l;
        }
        __syncthreads();   // Ps visible to all waves

        // prefetch next tile's Q fragments (hidden under PV)
        half8 qn0 = hz, qn1 = hz, qn2 = hz;
        if (t < 3) {
            const _Float16* qn = qp + (size_t)(t + 1) * 64 * EMBED;
            qn0 = *(const half8*)&qn[quad * 8];
            qn1 = *(const half8*)&qn[32 + quad * 8];
            if (quad < 2) qn2 = *(const half8*)&qn[64 + quad * 8];
        }

        // ---- load P fragments, release Ps ----
        const _Float16* pr = &Ps[(wave * 16 + l16) * LS];
        half8 pa0 = *(const half8*)&pr[quad * 8];
        half8 pa1 = *(const half8*)&pr[32 + quad * 8];
        half8 pa2 = (quad < 2) ? *(const half8*)&pr[64 + quad * 8] : hz;
        __syncthreads();   // Ps consumed; next iter may overwrite

        // ---- P @ V^T ----
        floatx4 acco[5] = {};
        #pragma unroll
        for (int dt = 0; dt < 5; ++dt) {
            const _Float16* vr = &Vt[(dt * 16 + l16) * LS];
            half8 b0 = *(const half8*)&vr[quad * 8];
            half8 b1 = *(const half8*)&vr[32 + quad * 8];
            half8 b2 = *(const half8*)&vr[64 + quad * 8];
            acco[dt] = __builtin_amdgcn_mfma_f32_16x16x32_f16(pa0, b0, acco[dt], 0, 0, 0);
            acco[dt] = __builtin_amdgcn_mfma_f32_16x16x32_f16(pa1, b1, acco[dt], 0, 0, 0);
            acco[dt] = __builtin_amdgcn_mfma_f32_16x16x32_f16(pa2, b2, acco[dt], 0, 0, 0);
        }

        // ---- store O ----
        #pragma unroll
        for (int r = 0; r < 4; ++r) {
            const size_t grow = row0 + t * 64 + wave * 16 + quad * 4 + r;
            #pragma unroll
            for (int dt = 0; dt < 5; ++dt)
                oh[grow * EMBED + h * HEAD + dt * 16 + l16] =
                    (_Float16)(acco[dt][r] * recip[r]);
        }

        qa0 = qn0; qa1 = qn1; qa2 = qn2;
    }
}

// ---------------------------------------------------------------------------
extern "C" void kernel_launch(void* const* d_in, const int* in_sizes, int n_in,
                              void* d_out, int out_size, void* d_ws, size_t ws_size,
                              hipStream_t stream)
{
    const float* x  = (const float*)d_in[0];
    const float* y  = (const float*)d_in[1];
    const float* Wq = (const float*)d_in[2];
    const float* bq = (const float*)d_in[3];
    const float* Wk = (const float*)d_in[4];
    const float* bk = (const float*)d_in[5];
    const float* Wv = (const float*)d_in[6];
    const float* bv = (const float*)d_in[7];
    const float* Wo = (const float*)d_in[8];
    const float* bo = (const float*)d_in[9];
    float* out = (float*)d_out;

    const size_t ME = (size_t)MROWS * EMBED;
    _Float16* xh  = (_Float16*)d_ws;                          // [M][640]
    _Float16* qh  = xh + ME;                                  // [M][640]
    _Float16* ah  = qh + ME;                                  // [M][640]
    _Float16* kh  = ah + ME;                                  // [64][77][80]
    _Float16* vth = kh  + (size_t)BATCH * NH * SEQS * HEAD;   // [64][80][80]
    _Float16* wqt = vth + (size_t)BATCH * NH * HEAD * 80;     // [640][640]
    _Float16* wot = wqt + (size_t)EMBED * EMBED;              // [640][640]
    _Float16* yh  = wot + (size_t)EMBED * EMBED;              // [640][768]
    _Float16* wkt = yh  + (size_t)640 * CROSS;                // [640][768]
    _Float16* wvt = wkt + (size_t)EMBED * CROSS;              // [640][768]

    // prep
    cvt_f32_f16<<<dim3(ME / (256 * 8)), 256, 0, stream>>>(x, xh);
    transpose_cvt<<<dim3(EMBED / 32, EMBED / 32), dim3(32, 8), 0, stream>>>(Wq, wqt, EMBED, EMBED);
    transpose_cvt<<<dim3(EMBED / 32, EMBED / 32), dim3(32, 8), 0, stream>>>(Wo, wot, EMBED, EMBED);
    transpose_cvt<<<dim3(EMBED / 32, CROSS / 32), dim3(32, 8), 0, stream>>>(Wk, wkt, CROSS, EMBED);
    transpose_cvt<<<dim3(EMBED / 32, CROSS / 32), dim3(32, 8), 0, stream>>>(Wv, wvt, CROSS, EMBED);
    cvt_y_f16<<<dim3(640 * CROSS / (256 * 8)), 256, 0, stream>>>(y, yh);
    zero_f16<<<dim3(((size_t)BATCH * NH * HEAD * 80 / 8 + 255) / 256), 256, 0, stream>>>(
        vth, (size_t)BATCH * NH * HEAD * 80 / 8);

    // 1) Q = (x @ Wq + bq) * 1/sqrt(80), f16 out
    gemm_f16<true><<<dim3(EMBED / 128, MROWS / 128), 256, 0, stream>>>(
        xh, wqt, bq, qh, MROWS, EMBED, EMBED, 0.11180339887498949f);
    // 2) K,V projections via MFMA -> attention layouts
    kv_gemm<<<dim3(EMBED / 64, 640 / 64, 2), 256, 0, stream>>>(
        yh, wkt, wvt, bk, bv, kh, vth);
    // 3) MFMA attention: persistent K/V, 256 q-rows per block
    attn_mfma<<<dim3(SEQT / 256, BATCH * NH), 256, 0, stream>>>(qh, kh, vth, ah);
    // 4) out = attn_out @ Wo + bo (fp32 out)
    gemm_f16<false><<<dim3(EMBED / 128, MROWS / 128), 256, 0, stream>>>(
        ah, wot, bo, out, MROWS, EMBED, EMBED, 1.0f);
}

// Round 2
// 306.582 us; speedup vs baseline: 1.1720x; 1.0581x over previous
//
#include <hip/hip_runtime.h>
#include <hip/hip_bf16.h>
#include <hip/hip_fp16.h>

#define EMBED 640
#define CROSS 768
#define NH 8
#define HEAD 80
#define BATCH 8
#define SEQT 4096
#define SEQS 77
#define MROWS (BATCH * SEQT)

typedef _Float16 half8 __attribute__((ext_vector_type(8)));
typedef float floatx4 __attribute__((ext_vector_type(4)));

__device__ __forceinline__ void lds_load16(const void* g, void* l) {
    __builtin_amdgcn_global_load_lds(
        (const __attribute__((address_space(1))) void*)g,
        (__attribute__((address_space(3))) void*)l, 16, 0, 0);
}

// ---------------------------------------------------------------------------
// fp32 -> f16 cast, 8 elems/thread (n divisible by 2048*... exact grids used).
// ---------------------------------------------------------------------------
__global__ __launch_bounds__(256) void cvt_f32_f16(
    const float* __restrict__ in, _Float16* __restrict__ out)
{
    size_t i = ((size_t)blockIdx.x * 256 + threadIdx.x) * 8;
    float4 a = *(const float4*)&in[i];
    float4 b = *(const float4*)&in[i + 4];
    half8 h;
    h[0] = (_Float16)a.x; h[1] = (_Float16)a.y;
    h[2] = (_Float16)a.z; h[3] = (_Float16)a.w;
    h[4] = (_Float16)b.x; h[5] = (_Float16)b.y;
    h[6] = (_Float16)b.z; h[7] = (_Float16)b.w;
    *(half8*)&out[i] = h;
}

// y [616*768] fp32 -> yh [640][768] f16, rows 616..639 zeroed.
__global__ __launch_bounds__(256) void cvt_y_f16(
    const float* __restrict__ y, _Float16* __restrict__ yh)
{
    size_t i = ((size_t)blockIdx.x * 256 + threadIdx.x) * 8;  // < 640*768
    half8 h = {};
    if (i < (size_t)BATCH * SEQS * CROSS) {
        float4 a = *(const float4*)&y[i];
        float4 b = *(const float4*)&y[i + 4];
        h[0] = (_Float16)a.x; h[1] = (_Float16)a.y;
        h[2] = (_Float16)a.z; h[3] = (_Float16)a.w;
        h[4] = (_Float16)b.x; h[5] = (_Float16)b.y;
        h[6] = (_Float16)b.z; h[7] = (_Float16)b.w;
    }
    *(half8*)&yh[i] = h;
}

__global__ __launch_bounds__(256) void zero_f16(_Float16* __restrict__ p, size_t n8)
{
    size_t i = (size_t)blockIdx.x * 256 + threadIdx.x;
    if (i < n8) *(half8*)&p[i * 8] = (half8){};
}

// ---------------------------------------------------------------------------
// W [K,N] fp32  ->  Wt [N,K] f16   (tiled transpose, 32x32)
// ---------------------------------------------------------------------------
__global__ __launch_bounds__(256) void transpose_cvt(
    const float* __restrict__ W, _Float16* __restrict__ Wt, int K, int N)
{
    __shared__ float t[32][33];
    const int k0 = blockIdx.y * 32, n0 = blockIdx.x * 32;
    for (int r = threadIdx.y; r < 32; r += 8)
        t[r][threadIdx.x] = W[(size_t)(k0 + r) * N + n0 + threadIdx.x];
    __syncthreads();
    for (int r = threadIdx.y; r < 32; r += 8)
        Wt[(size_t)(n0 + r) * K + k0 + threadIdx.x] = (_Float16)t[threadIdx.x][r];
}

// ---------------------------------------------------------------------------
// f16 MFMA GEMM (m97 structure): C = A[M,K] @ Bt[N,K]^T + bias, then *scale.
// HALF_OUT: write f16 (for Q, scale=1/sqrt(80) folded) else fp32.
// v3: (a) XCD-aware block remap: the gridDim.x n-tiles sharing one A-panel
//     map to the SAME XCD (bijective since nwg%8==0) -> per-XCD L2 holds the
//     A working set, kills the 2.5x A over-fetch.
//     (b) LDS chunk XOR-swizzle (both-sides, rule: linear gload_lds dest +
//     pre-swizzled global source + swizzled read) -> ds_read_b128 2-way max.
// ---------------------------------------------------------------------------
template <bool HALF_OUT>
__global__ __launch_bounds__(256) void gemm_f16(
    const _Float16* __restrict__ A,   // [M,K] f16
    const _Float16* __restrict__ Bt,  // [N,K] f16
    const float* __restrict__ bias,
    void* __restrict__ Cout, int M, int N, int K, float scale)
{
    __shared__ _Float16 As[128 * 32];
    __shared__ _Float16 Bs[128 * 32];

    const int tid  = threadIdx.x;
    const int wave = tid >> 6;
    const int lane = tid & 63;
    const int quad = lane >> 4;
    const int l16  = lane & 15;

    // XCD-aware remap: linear id l -> xcd = l&7; within an XCD, the
    // gridDim.x consecutive blocks share one m-panel (A reuse in L2).
    const int l   = blockIdx.y * gridDim.x + blockIdx.x;
    const int inner = l >> 3;
    const int p   = (l & 7) + 8 * (inner / gridDim.x);
    const int nt  = inner % gridDim.x;
    const int m0 = p * 128, n0 = nt * 128;
    const int wm = (wave >> 1) * 64, wn = (wave & 1) * 64;

    const int row = tid >> 2;
    // swizzled global source chunk: LDS (row, q) holds global chunk q ^ s(row),
    // s(row) = (row>>1)&3  (same for row and row+64: 32 == 0 mod 4)
    const int kch = ((tid & 3) ^ ((row >> 1) & 3)) * 8;
    // swizzled read chunk: want global chunk 'quad' at row wm+i*16+l16;
    // s(row) there reduces to (l16>>1)&3 since wm,i*16 are 0 mod 32.
    const int cq  = (quad ^ ((l16 >> 1) & 3)) * 8;

    floatx4 acc[4][4] = {};

    for (int k0 = 0; k0 < K; k0 += 32) {
        const _Float16* ga0 = &A [(size_t)(m0 + row)      * K + k0 + kch];
        const _Float16* ga1 = &A [(size_t)(m0 + 64 + row) * K + k0 + kch];
        const _Float16* gb0 = &Bt[(size_t)(n0 + row)      * K + k0 + kch];
        const _Float16* gb1 = &Bt[(size_t)(n0 + 64 + row) * K + k0 + kch];
        lds_load16(ga0, &As[wave * 512]);
        lds_load16(ga1, &As[2048 + wave * 512]);
        lds_load16(gb0, &Bs[wave * 512]);
        lds_load16(gb1, &Bs[2048 + wave * 512]);
        __syncthreads();

        half8 a[4], b[4];
        #pragma unroll
        for (int i = 0; i < 4; ++i)
            a[i] = *(const half8*)&As[(wm + i * 16 + l16) * 32 + cq];
        #pragma unroll
        for (int j = 0; j < 4; ++j)
            b[j] = *(const half8*)&Bs[(wn + j * 16 + l16) * 32 + cq];
        #pragma unroll
        for (int i = 0; i < 4; ++i)
            #pragma unroll
            for (int j = 0; j < 4; ++j)
                acc[i][j] = __builtin_amdgcn_mfma_f32_16x16x32_f16(
                    a[i], b[j], acc[i][j], 0, 0, 0);
        __syncthreads();
    }

    float bcol[4];
    #pragma unroll
    for (int j = 0; j < 4; ++j) bcol[j] = bias[n0 + wn + j * 16 + l16];
    #pragma unroll
    for (int i = 0; i < 4; ++i)
        #pragma unroll
        for (int r = 0; r < 4; ++r) {
            const int m = m0 + wm + i * 16 + quad * 4 + r;
            #pragma unroll
            for (int j = 0; j < 4; ++j) {
                float v = (acc[i][j][r] + bcol[j]) * scale;
                const size_t off = (size_t)m * N + n0 + wn + j * 16 + l16;
                if (HALF_OUT) ((_Float16*)Cout)[off] = (_Float16)v;
                else          ((float*)Cout)[off] = v;
            }
        }
}

// ---------------------------------------------------------------------------
// K/V projection via MFMA. 64x64 tiles, 4 waves (wave w = cols w*16..w*16+15).
// A = yh [640][768] f16 (rows 616+ zero), B = Wkt/Wvt [640][768] f16.
// Epilogue scatters f16 into attention layouts:
//   kh [bh][s(77)][d(80)], vth[bh][d(80)][s(80, pads pre-zeroed)]
// ---------------------------------------------------------------------------
__global__ __launch_bounds__(256) void kv_gemm(
    const _Float16* __restrict__ yh,
    const _Float16* __restrict__ Wkt, const _Float16* __restrict__ Wvt,
    const float* __restrict__ bk, const float* __restrict__ bv,
    _Float16* __restrict__ kh, _Float16* __restrict__ vth)
{
    __shared__ _Float16 As[64 * 32];
    __shared__ _Float16 Bs[64 * 32];

    const int tid = threadIdx.x;
    const int wave = tid >> 6, lane = tid & 63;
    const int quad = lane >> 4, l16 = lane & 15;
    const int m0 = blockIdx.y * 64, n0 = blockIdx.x * 64;
    const bool isV = blockIdx.z != 0;
    const _Float16* Bt = isV ? Wvt : Wkt;
    const float* bias  = isV ? bv : bk;

    const int row = tid >> 2;        // 0..63
    const int kch = (tid & 3) * 8;   // k chunk (8 f16 = 16 B)

    floatx4 acc[4] = {};

    for (int k0 = 0; k0 < CROSS; k0 += 32) {
        lds_load16(&yh[(size_t)(m0 + row) * CROSS + k0 + kch], &As[wave * 512]);
        lds_load16(&Bt[(size_t)(n0 + row) * CROSS + k0 + kch], &Bs[wave * 512]);
        __syncthreads();
        half8 b = *(const half8*)&Bs[(wave * 16 + l16) * 32 + quad * 8];
        #pragma unroll
        for (int i = 0; i < 4; ++i) {
            half8 a = *(const half8*)&As[(i * 16 + l16) * 32 + quad * 8];
            acc[i] = __builtin_amdgcn_mfma_f32_16x16x32_f16(a, b, acc[i], 0, 0, 0);
        }
        __syncthreads();
    }

    const int n = n0 + wave * 16 + l16;     // 0..639
    const int h = n / HEAD, d = n % HEAD;
    const float bb = bias[n];
    #pragma unroll
    for (int i = 0; i < 4; ++i)
        #pragma unroll
        for (int r = 0; r < 4; ++r) {
            const int m = m0 + i * 16 + quad * 4 + r;
            if (m >= BATCH * SEQS) continue;
            const int b_ = m / SEQS, s = m % SEQS;
            const int bh = b_ * NH + h;
            const float v = acc[i][r] + bb;
            if (isV) vth[(size_t)bh * (HEAD * 80) + d * 80 + s] = (_Float16)v;
            else     kh [(size_t)bh * (SEQS * HEAD) + s * HEAD + d] = (_Float16)v;
        }
}

// ---------------------------------------------------------------------------
// MFMA attention v2: persistent K/V per block.
// Grid (16, 64): block = one (b,h) x 256 q-rows (4 tiles of 64).
// ---------------------------------------------------------------------------
__global__ __launch_bounds__(256, 4) void attn_mfma(
    const _Float16* __restrict__ qh,   // [M][EMBED], 1/sqrt(80) pre-folded
    const _Float16* __restrict__ kh,   // [64][77][80]
    const _Float16* __restrict__ vth,  // [64][80][80]
    _Float16* __restrict__ oh)         // [M][EMBED]
{
    constexpr int LS = 88;             // f16 LDS row stride (80 data + 8 pad)
    __shared__ _Float16 lds[(80 + 80 + 64) * LS + 8];
    _Float16* Ks = lds;                // [80][LS]  rows 77..79 zeroed
    _Float16* Vt = lds + 80 * LS;      // [80][LS]
    _Float16* Ps = lds + 160 * LS;     // [64][LS]

    const int tid = threadIdx.x;
    const int wave = tid >> 6, lane = tid & 63;
    const int quad = lane >> 4, l16 = lane & 15;
    const int bh = blockIdx.y;
    const int b = bh >> 3, h = bh & 7;
    const size_t row0 = (size_t)b * SEQT + (size_t)blockIdx.x * 256;
    const half8 hz = {};

    // Q base for this lane's A-fragment row (A row index = l16)
    const _Float16* qp = qh + (row0 + wave * 16 + l16) * EMBED + h * HEAD;

    // tile 0 Q fragments (overlap with staging below)
    half8 qa0 = *(const half8*)&qp[quad * 8];
    half8 qa1 = *(const half8*)&qp[32 + quad * 8];
    half8 qa2 = (quad < 2) ? *(const half8*)&qp[64 + quad * 8] : hz;

    // stage K (rows >= 77 and pad chunk zeroed)
    for (int idx = tid; idx < 80 * 11; idx += 256) {
        const int s = idx / 11, c = idx % 11;
        half8 v = hz;
        if (s < SEQS && c < 10)
            v = *(const half8*)&kh[(size_t)bh * (SEQS * HEAD) + s * HEAD + c * 8];
        *(half8*)&Ks[s * LS + c * 8] = v;
    }
    // stage V^T (pad chunk zeroed; cols s>=77 are zero in global)
    for (int idx = tid; idx < 80 * 11; idx += 256) {
        const int d = idx / 11, c = idx % 11;
        half8 v = hz;
        if (c < 10)
            v = *(const half8*)&vth[(size_t)bh * (HEAD * 80) + d * 80 + c * 8];
        *(half8*)&Vt[d * LS + c * 8] = v;
    }
    __syncthreads();

    for (int t = 0; t < 4; ++t) {
        // ---- QK^T ----
        floatx4 accs[5] = {};
        #pragma unroll
        for (int st = 0; st < 5; ++st) {
            const _Float16* kr = &Ks[(st * 16 + l16) * LS];
            half8 b0 = *(const half8*)&kr[quad * 8];
            half8 b1 = *(const half8*)&kr[32 + quad * 8];
            half8 b2 = *(const half8*)&kr[64 + quad * 8];
            accs[st] = __builtin_amdgcn_mfma_f32_16x16x32_f16(qa0, b0, accs[st], 0, 0, 0);
            accs[st] = __builtin_amdgcn_mfma_f32_16x16x32_f16(qa1, b1, accs[st], 0, 0, 0);
            accs[st] = __builtin_amdgcn_mfma_f32_16x16x32_f16(qa2, b2, accs[st], 0, 0, 0);
        }
        if (l16 >= 13) {
            accs[4][0] = -1e30f; accs[4][1] = -1e30f;
            accs[4][2] = -1e30f; accs[4][3] = -1e30f;
        }

        // ---- softmax (row = wave*16 + quad*4 + r, cols st*16 + l16) ----
        float recip[4];
        #pragma unroll
        for (int r = 0; r < 4; ++r) {
            float m = accs[0][r];
            #pragma unroll
            for (int st = 1; st < 5; ++st) m = fmaxf(m, accs[st][r]);
            m = fmaxf(m, __shfl_xor(m, 1));
            m = fmaxf(m, __shfl_xor(m, 2));
            m = fmaxf(m, __shfl_xor(m, 4));
            m = fmaxf(m, __shfl_xor(m, 8));
            float l = 0.f;
            const int row = wave * 16 + quad * 4 + r;
            #pragma unroll
            for (int st = 0; st < 5; ++st) {
                float e = __expf(accs[st][r] - m);
                l += e;
                Ps[row * LS + st * 16 + l16] = (_Float16)e;
            }
            l += __shfl_xor(l, 1);
            l += __shfl_xor(l, 2);
            l += __shfl_xor(l, 4);
            l += __shfl_xor(l, 8);
            recip[r] = 1.0f / l;
        }
        __syncthreads();   // Ps visible to all waves

        // prefetch next tile's Q fragments (hidden under PV)
        half8 qn0 = hz, qn1 = hz, qn2 = hz;
        if (t < 3) {
            const _Float16* qn = qp + (size_t)(t + 1) * 64 * EMBED;
            qn0 = *(const half8*)&qn[quad * 8];
            qn1 = *(const half8*)&qn[32 + quad * 8];
            if (quad < 2) qn2 = *(const half8*)&qn[64 + quad * 8];
        }

        // ---- load P fragments, release Ps ----
        const _Float16* pr = &Ps[(wave * 16 + l16) * LS];
        half8 pa0 = *(const half8*)&pr[quad * 8];
        half8 pa1 = *(const half8*)&pr[32 + quad * 8];
        half8 pa2 = (quad < 2) ? *(const half8*)&pr[64 + quad * 8] : hz;
        __syncthreads();   // Ps consumed; next iter may overwrite

        // ---- P @ V^T ----
        floatx4 acco[5] = {};
        #pragma unroll
        for (int dt = 0; dt < 5; ++dt) {
            const _Float16* vr = &Vt[(dt * 16 + l16) * LS];
            half8 b0 = *(const half8*)&vr[quad * 8];
            half8 b1 = *(const half8*)&vr[32 + quad * 8];
            half8 b2 = *(const half8*)&vr[64 + quad * 8];
            acco[dt] = __builtin_amdgcn_mfma_f32_16x16x32_f16(pa0, b0, acco[dt], 0, 0, 0);
            acco[dt] = __builtin_amdgcn_mfma_f32_16x16x32_f16(pa1, b1, acco[dt], 0, 0, 0);
            acco[dt] = __builtin_amdgcn_mfma_f32_16x16x32_f16(pa2, b2, acco[dt], 0, 0, 0);
        }

        // ---- store O ----
        #pragma unroll
        for (int r = 0; r < 4; ++r) {
            const size_t grow = row0 + t * 64 + wave * 16 + quad * 4 + r;
            #pragma unroll
            for (int dt = 0; dt < 5; ++dt)
                oh[grow * EMBED + h * HEAD + dt * 16 + l16] =
                    (_Float16)(acco[dt][r] * recip[r]);
        }

        qa0 = qn0; qa1 = qn1; qa2 = qn2;
    }
}

// ---------------------------------------------------------------------------
extern "C" void kernel_launch(void* const* d_in, const int* in_sizes, int n_in,
                              void* d_out, int out_size, void* d_ws, size_t ws_size,
                              hipStream_t stream)
{
    const float* x  = (const float*)d_in[0];
    const float* y  = (const float*)d_in[1];
    const float* Wq = (const float*)d_in[2];
    const float* bq = (const float*)d_in[3];
    const float* Wk = (const float*)d_in[4];
    const float* bk = (const float*)d_in[5];
    const float* Wv = (const float*)d_in[6];
    const float* bv = (const float*)d_in[7];
    const float* Wo = (const float*)d_in[8];
    const float* bo = (const float*)d_in[9];
    float* out = (float*)d_out;

    const size_t ME = (size_t)MROWS * EMBED;
    _Float16* xh  = (_Float16*)d_ws;                          // [M][640]
    _Float16* qh  = xh + ME;                                  // [M][640]
    _Float16* ah  = qh + ME;                                  // [M][640]
    _Float16* kh  = ah + ME;                                  // [64][77][80]
    _Float16* vth = kh  + (size_t)BATCH * NH * SEQS * HEAD;   // [64][80][80]
    _Float16* wqt = vth + (size_t)BATCH * NH * HEAD * 80;     // [640][640]
    _Float16* wot = wqt + (size_t)EMBED * EMBED;              // [640][640]
    _Float16* yh  = wot + (size_t)EMBED * EMBED;              // [640][768]
    _Float16* wkt = yh  + (size_t)640 * CROSS;                // [640][768]
    _Float16* wvt = wkt + (size_t)EMBED * CROSS;              // [640][768]

    // prep
    cvt_f32_f16<<<dim3(ME / (256 * 8)), 256, 0, stream>>>(x, xh);
    transpose_cvt<<<dim3(EMBED / 32, EMBED / 32), dim3(32, 8), 0, stream>>>(Wq, wqt, EMBED, EMBED);
    transpose_cvt<<<dim3(EMBED / 32, EMBED / 32), dim3(32, 8), 0, stream>>>(Wo, wot, EMBED, EMBED);
    transpose_cvt<<<dim3(EMBED / 32, CROSS / 32), dim3(32, 8), 0, stream>>>(Wk, wkt, CROSS, EMBED);
    transpose_cvt<<<dim3(EMBED / 32, CROSS / 32), dim3(32, 8), 0, stream>>>(Wv, wvt, CROSS, EMBED);
    cvt_y_f16<<<dim3(640 * CROSS / (256 * 8)), 256, 0, stream>>>(y, yh);
    zero_f16<<<dim3(((size_t)BATCH * NH * HEAD * 80 / 8 + 255) / 256), 256, 0, stream>>>(
        vth, (size_t)BATCH * NH * HEAD * 80 / 8);

    // 1) Q = (x @ Wq + bq) * 1/sqrt(80), f16 out
    gemm_f16<true><<<dim3(EMBED / 128, MROWS / 128), 256, 0, stream>>>(
        xh, wqt, bq, qh, MROWS, EMBED, EMBED, 0.11180339887498949f);
    // 2) K,V projections via MFMA -> attention layouts
    kv_gemm<<<dim3(EMBED / 64, 640 / 64, 2), 256, 0, stream>>>(
        yh, wkt, wvt, bk, bv, kh, vth);
    // 3) MFMA attention: persistent K/V, 256 q-rows per block
    attn_mfma<<<dim3(SEQT / 256, BATCH * NH), 256, 0, stream>>>(qh, kh, vth, ah);
    // 4) out = attn_out @ Wo + bo (fp32 out)
    gemm_f16<false><<<dim3(EMBED / 128, MROWS / 128), 256, 0, stream>>>(
        ah, wot, bo, out, MROWS, EMBED, EMBED, 1.0f);
}

// Round 3
// 301.151 us; speedup vs baseline: 1.1931x; 1.0180x over previous
//
#include <hip/hip_runtime.h>
#include <hip/hip_bf16.h>
#include <hip/hip_fp16.h>

#define EMBED 640
#define CROSS 768
#define NH 8
#define HEAD 80
#define BATCH 8
#define SEQT 4096
#define SEQS 77
#define MROWS (BATCH * SEQT)

typedef _Float16 half8 __attribute__((ext_vector_type(8)));
typedef float floatx4 __attribute__((ext_vector_type(4)));

__device__ __forceinline__ void lds_load16(const void* g, void* l) {
    __builtin_amdgcn_global_load_lds(
        (const __attribute__((address_space(1))) void*)g,
        (__attribute__((address_space(3))) void*)l, 16, 0, 0);
}

// ---------------------------------------------------------------------------
// fp32 -> f16 cast, 8 elems/thread (n divisible by 2048*... exact grids used).
// ---------------------------------------------------------------------------
__global__ __launch_bounds__(256) void cvt_f32_f16(
    const float* __restrict__ in, _Float16* __restrict__ out)
{
    size_t i = ((size_t)blockIdx.x * 256 + threadIdx.x) * 8;
    float4 a = *(const float4*)&in[i];
    float4 b = *(const float4*)&in[i + 4];
    half8 h;
    h[0] = (_Float16)a.x; h[1] = (_Float16)a.y;
    h[2] = (_Float16)a.z; h[3] = (_Float16)a.w;
    h[4] = (_Float16)b.x; h[5] = (_Float16)b.y;
    h[6] = (_Float16)b.z; h[7] = (_Float16)b.w;
    *(half8*)&out[i] = h;
}

// y [616*768] fp32 -> yh [640][768] f16, rows 616..639 zeroed.
__global__ __launch_bounds__(256) void cvt_y_f16(
    const float* __restrict__ y, _Float16* __restrict__ yh)
{
    size_t i = ((size_t)blockIdx.x * 256 + threadIdx.x) * 8;  // < 640*768
    half8 h = {};
    if (i < (size_t)BATCH * SEQS * CROSS) {
        float4 a = *(const float4*)&y[i];
        float4 b = *(const float4*)&y[i + 4];
        h[0] = (_Float16)a.x; h[1] = (_Float16)a.y;
        h[2] = (_Float16)a.z; h[3] = (_Float16)a.w;
        h[4] = (_Float16)b.x; h[5] = (_Float16)b.y;
        h[6] = (_Float16)b.z; h[7] = (_Float16)b.w;
    }
    *(half8*)&yh[i] = h;
}

__global__ __launch_bounds__(256) void zero_f16(_Float16* __restrict__ p, size_t n8)
{
    size_t i = (size_t)blockIdx.x * 256 + threadIdx.x;
    if (i < n8) *(half8*)&p[i * 8] = (half8){};
}

// ---------------------------------------------------------------------------
// W [K,N] fp32  ->  Wt [N,K] f16   (tiled transpose, 32x32)
// ---------------------------------------------------------------------------
__global__ __launch_bounds__(256) void transpose_cvt(
    const float* __restrict__ W, _Float16* __restrict__ Wt, int K, int N)
{
    __shared__ float t[32][33];
    const int k0 = blockIdx.y * 32, n0 = blockIdx.x * 32;
    for (int r = threadIdx.y; r < 32; r += 8)
        t[r][threadIdx.x] = W[(size_t)(k0 + r) * N + n0 + threadIdx.x];
    __syncthreads();
    for (int r = threadIdx.y; r < 32; r += 8)
        Wt[(size_t)(n0 + r) * K + k0 + threadIdx.x] = (_Float16)t[threadIdx.x][r];
}

// ---------------------------------------------------------------------------
// f16 MFMA GEMM: C = A[M,K] @ Bt[N,K]^T + bias, then *scale.
// v4: 3-deep staged pipeline with counted vmcnt (T3/T4 minimum form).
//   - triple-buffered LDS (BK=32, 48 KB total -> 3 blocks/CU)
//   - raw s_barrier + "s_waitcnt vmcnt(8)" in steady state (never drain to 0
//     in the loop) so 2 tiles of global_load_lds stay in flight across
//     barriers; stage(t+3) is issued into the buffer freed by compute(t).
//   - keeps r2's XCD-aware remap + LDS chunk XOR swizzle (conflicts = 0).
// ---------------------------------------------------------------------------
template <bool HALF_OUT>
__global__ __launch_bounds__(256) void gemm_f16(
    const _Float16* __restrict__ A,   // [M,K] f16
    const _Float16* __restrict__ Bt,  // [N,K] f16
    const float* __restrict__ bias,
    void* __restrict__ Cout, int M, int N, int K, float scale)
{
    __shared__ _Float16 As[3][128 * 32];
    __shared__ _Float16 Bs[3][128 * 32];

    const int tid  = threadIdx.x;
    const int wave = tid >> 6;
    const int lane = tid & 63;
    const int quad = lane >> 4;
    const int l16  = lane & 15;

    // XCD-aware remap: linear id l -> xcd = l&7; within an XCD, the
    // gridDim.x consecutive blocks share one m-panel (A reuse in L2).
    const int l   = blockIdx.y * gridDim.x + blockIdx.x;
    const int inner = l >> 3;
    const int p   = (l & 7) + 8 * (inner / gridDim.x);
    const int nt  = inner % gridDim.x;
    const int m0 = p * 128, n0 = nt * 128;
    const int wm = (wave >> 1) * 64, wn = (wave & 1) * 64;

    const int row = tid >> 2;
    // swizzled global source chunk: LDS (row, q) holds global chunk q ^ s(row)
    const int kch = ((tid & 3) ^ ((row >> 1) & 3)) * 8;
    // swizzled read chunk (s(row) reduces to (l16>>1)&3: wm, i*16 are 0 mod 32)
    const int cq  = (quad ^ ((l16 >> 1) & 3)) * 8;

    const _Float16* pa0 = &A [(size_t)(m0 + row)      * K + kch];
    const _Float16* pa1 = &A [(size_t)(m0 + 64 + row) * K + kch];
    const _Float16* pb0 = &Bt[(size_t)(n0 + row)      * K + kch];
    const _Float16* pb1 = &Bt[(size_t)(n0 + 64 + row) * K + kch];

    const int NT = K / 32;   // 20

    auto stage = [&](int t) {
        const int bf = t % 3;
        const int off = t * 32;
        lds_load16(pa0 + off, &As[bf][wave * 512]);
        lds_load16(pa1 + off, &As[bf][2048 + wave * 512]);
        lds_load16(pb0 + off, &Bs[bf][wave * 512]);
        lds_load16(pb1 + off, &Bs[bf][2048 + wave * 512]);
    };
    stage(0); stage(1); stage(2);     // 12 loads in flight

    floatx4 acc[4][4] = {};

    for (int t = 0; t < NT; ++t) {
        // wait until stage(t) has landed; keep stages t+1,t+2 in flight
        const int rem = NT - 1 - t;
        if (rem >= 2)      asm volatile("s_waitcnt vmcnt(8)" ::: "memory");
        else if (rem == 1) asm volatile("s_waitcnt vmcnt(4)" ::: "memory");
        else               asm volatile("s_waitcnt vmcnt(0)" ::: "memory");
        __builtin_amdgcn_s_barrier();   // all waves' stage(t) visible

        const _Float16* as = As[t % 3];
        const _Float16* bs = Bs[t % 3];
        half8 a[4], b[4];
        #pragma unroll
        for (int i = 0; i < 4; ++i)
            a[i] = *(const half8*)&as[(wm + i * 16 + l16) * 32 + cq];
        #pragma unroll
        for (int j = 0; j < 4; ++j)
            b[j] = *(const half8*)&bs[(wn + j * 16 + l16) * 32 + cq];
        #pragma unroll
        for (int i = 0; i < 4; ++i)
            #pragma unroll
            for (int j = 0; j < 4; ++j)
                acc[i][j] = __builtin_amdgcn_mfma_f32_16x16x32_f16(
                    a[i], b[j], acc[i][j], 0, 0, 0);

        // all this wave's ds_reads retired (MFMA consumption forces it, but
        // make it explicit), then sync before re-staging this buffer
        asm volatile("s_waitcnt lgkmcnt(0)" ::: "memory");
        __builtin_amdgcn_s_barrier();
        if (t + 3 < NT) stage(t + 3);
    }

    float bcol[4];
    #pragma unroll
    for (int j = 0; j < 4; ++j) bcol[j] = bias[n0 + wn + j * 16 + l16];
    #pragma unroll
    for (int i = 0; i < 4; ++i)
        #pragma unroll
        for (int r = 0; r < 4; ++r) {
            const int m = m0 + wm + i * 16 + quad * 4 + r;
            #pragma unroll
            for (int j = 0; j < 4; ++j) {
                float v = (acc[i][j][r] + bcol[j]) * scale;
                const size_t off = (size_t)m * N + n0 + wn + j * 16 + l16;
                if (HALF_OUT) ((_Float16*)Cout)[off] = (_Float16)v;
                else          ((float*)Cout)[off] = v;
            }
        }
}

// ---------------------------------------------------------------------------
// K/V projection via MFMA. 64x64 tiles, 4 waves (wave w = cols w*16..w*16+15).
// A = yh [640][768] f16 (rows 616+ zero), B = Wkt/Wvt [640][768] f16.
// Epilogue scatters f16 into attention layouts:
//   kh [bh][s(77)][d(80)], vth[bh][d(80)][s(80, pads pre-zeroed)]
// ---------------------------------------------------------------------------
__global__ __launch_bounds__(256) void kv_gemm(
    const _Float16* __restrict__ yh,
    const _Float16* __restrict__ Wkt, const _Float16* __restrict__ Wvt,
    const float* __restrict__ bk, const float* __restrict__ bv,
    _Float16* __restrict__ kh, _Float16* __restrict__ vth)
{
    __shared__ _Float16 As[64 * 32];
    __shared__ _Float16 Bs[64 * 32];

    const int tid = threadIdx.x;
    const int wave = tid >> 6, lane = tid & 63;
    const int quad = lane >> 4, l16 = lane & 15;
    const int m0 = blockIdx.y * 64, n0 = blockIdx.x * 64;
    const bool isV = blockIdx.z != 0;
    const _Float16* Bt = isV ? Wvt : Wkt;
    const float* bias  = isV ? bv : bk;

    const int row = tid >> 2;        // 0..63
    const int kch = (tid & 3) * 8;   // k chunk (8 f16 = 16 B)

    floatx4 acc[4] = {};

    for (int k0 = 0; k0 < CROSS; k0 += 32) {
        lds_load16(&yh[(size_t)(m0 + row) * CROSS + k0 + kch], &As[wave * 512]);
        lds_load16(&Bt[(size_t)(n0 + row) * CROSS + k0 + kch], &Bs[wave * 512]);
        __syncthreads();
        half8 b = *(const half8*)&Bs[(wave * 16 + l16) * 32 + quad * 8];
        #pragma unroll
        for (int i = 0; i < 4; ++i) {
            half8 a = *(const half8*)&As[(i * 16 + l16) * 32 + quad * 8];
            acc[i] = __builtin_amdgcn_mfma_f32_16x16x32_f16(a, b, acc[i], 0, 0, 0);
        }
        __syncthreads();
    }

    const int n = n0 + wave * 16 + l16;     // 0..639
    const int h = n / HEAD, d = n % HEAD;
    const float bb = bias[n];
    #pragma unroll
    for (int i = 0; i < 4; ++i)
        #pragma unroll
        for (int r = 0; r < 4; ++r) {
            const int m = m0 + i * 16 + quad * 4 + r;
            if (m >= BATCH * SEQS) continue;
            const int b_ = m / SEQS, s = m % SEQS;
            const int bh = b_ * NH + h;
            const float v = acc[i][r] + bb;
            if (isV) vth[(size_t)bh * (HEAD * 80) + d * 80 + s] = (_Float16)v;
            else     kh [(size_t)bh * (SEQS * HEAD) + s * HEAD + d] = (_Float16)v;
        }
}

// ---------------------------------------------------------------------------
// MFMA attention v2: persistent K/V per block.
// Grid (16, 64): block = one (b,h) x 256 q-rows (4 tiles of 64).
// ---------------------------------------------------------------------------
__global__ __launch_bounds__(256, 4) void attn_mfma(
    const _Float16* __restrict__ qh,   // [M][EMBED], 1/sqrt(80) pre-folded
    const _Float16* __restrict__ kh,   // [64][77][80]
    const _Float16* __restrict__ vth,  // [64][80][80]
    _Float16* __restrict__ oh)         // [M][EMBED]
{
    constexpr int LS = 88;             // f16 LDS row stride (80 data + 8 pad)
    __shared__ _Float16 lds[(80 + 80 + 64) * LS + 8];
    _Float16* Ks = lds;                // [80][LS]  rows 77..79 zeroed
    _Float16* Vt = lds + 80 * LS;      // [80][LS]
    _Float16* Ps = lds + 160 * LS;     // [64][LS]

    const int tid = threadIdx.x;
    const int wave = tid >> 6, lane = tid & 63;
    const int quad = lane >> 4, l16 = lane & 15;
    const int bh = blockIdx.y;
    const int b = bh >> 3, h = bh & 7;
    const size_t row0 = (size_t)b * SEQT + (size_t)blockIdx.x * 256;
    const half8 hz = {};

    // Q base for this lane's A-fragment row (A row index = l16)
    const _Float16* qp = qh + (row0 + wave * 16 + l16) * EMBED + h * HEAD;

    // tile 0 Q fragments (overlap with staging below)
    half8 qa0 = *(const half8*)&qp[quad * 8];
    half8 qa1 = *(const half8*)&qp[32 + quad * 8];
    half8 qa2 = (quad < 2) ? *(const half8*)&qp[64 + quad * 8] : hz;

    // stage K (rows >= 77 and pad chunk zeroed)
    for (int idx = tid; idx < 80 * 11; idx += 256) {
        const int s = idx / 11, c = idx % 11;
        half8 v = hz;
        if (s < SEQS && c < 10)
            v = *(const half8*)&kh[(size_t)bh * (SEQS * HEAD) + s * HEAD + c * 8];
        *(half8*)&Ks[s * LS + c * 8] = v;
    }
    // stage V^T (pad chunk zeroed; cols s>=77 are zero in global)
    for (int idx = tid; idx < 80 * 11; idx += 256) {
        const int d = idx / 11, c = idx % 11;
        half8 v = hz;
        if (c < 10)
            v = *(const half8*)&vth[(size_t)bh * (HEAD * 80) + d * 80 + c * 8];
        *(half8*)&Vt[d * LS + c * 8] = v;
    }
    __syncthreads();

    for (int t = 0; t < 4; ++t) {
        // ---- QK^T ----
        floatx4 accs[5] = {};
        #pragma unroll
        for (int st = 0; st < 5; ++st) {
            const _Float16* kr = &Ks[(st * 16 + l16) * LS];
            half8 b0 = *(const half8*)&kr[quad * 8];
            half8 b1 = *(const half8*)&kr[32 + quad * 8];
            half8 b2 = *(const half8*)&kr[64 + quad * 8];
            accs[st] = __builtin_amdgcn_mfma_f32_16x16x32_f16(qa0, b0, accs[st], 0, 0, 0);
            accs[st] = __builtin_amdgcn_mfma_f32_16x16x32_f16(qa1, b1, accs[st], 0, 0, 0);
            accs[st] = __builtin_amdgcn_mfma_f32_16x16x32_f16(qa2, b2, accs[st], 0, 0, 0);
        }
        if (l16 >= 13) {
            accs[4][0] = -1e30f; accs[4][1] = -1e30f;
            accs[4][2] = -1e30f; accs[4][3] = -1e30f;
        }

        // ---- softmax (row = wave*16 + quad*4 + r, cols st*16 + l16) ----
        float recip[4];
        #pragma unroll
        for (int r = 0; r < 4; ++r) {
            float m = accs[0][r];
            #pragma unroll
            for (int st = 1; st < 5; ++st) m = fmaxf(m, accs[st][r]);
            m = fmaxf(m, __shfl_xor(m, 1));
            m = fmaxf(m, __shfl_xor(m, 2));
            m = fmaxf(m, __shfl_xor(m, 4));
            m = fmaxf(m, __shfl_xor(m, 8));
            float l = 0.f;
            const int row = wave * 16 + quad * 4 + r;
            #pragma unroll
            for (int st = 0; st < 5; ++st) {
                float e = __expf(accs[st][r] - m);
                l += e;
                Ps[row * LS + st * 16 + l16] = (_Float16)e;
            }
            l += __shfl_xor(l, 1);
            l += __shfl_xor(l, 2);
            l += __shfl_xor(l, 4);
            l += __shfl_xor(l, 8);
            recip[r] = 1.0f / l;
        }
        __syncthreads();   // Ps visible to all waves

        // prefetch next tile's Q fragments (hidden under PV)
        half8 qn0 = hz, qn1 = hz, qn2 = hz;
        if (t < 3) {
            const _Float16* qn = qp + (size_t)(t + 1) * 64 * EMBED;
            qn0 = *(const half8*)&qn[quad * 8];
            qn1 = *(const half8*)&qn[32 + quad * 8];
            if (quad < 2) qn2 = *(const half8*)&qn[64 + quad * 8];
        }

        // ---- load P fragments, release Ps ----
        const _Float16* pr = &Ps[(wave * 16 + l16) * LS];
        half8 pa0 = *(const half8*)&pr[quad * 8];
        half8 pa1 = *(const half8*)&pr[32 + quad * 8];
        half8 pa2 = (quad < 2) ? *(const half8*)&pr[64 + quad * 8] : hz;
        __syncthreads();   // Ps consumed; next iter may overwrite

        // ---- P @ V^T ----
        floatx4 acco[5] = {};
        #pragma unroll
        for (int dt = 0; dt < 5; ++dt) {
            const _Float16* vr = &Vt[(dt * 16 + l16) * LS];
            half8 b0 = *(const half8*)&vr[quad * 8];
            half8 b1 = *(const half8*)&vr[32 + quad * 8];
            half8 b2 = *(const half8*)&vr[64 + quad * 8];
            acco[dt] = __builtin_amdgcn_mfma_f32_16x16x32_f16(pa0, b0, acco[dt], 0, 0, 0);
            acco[dt] = __builtin_amdgcn_mfma_f32_16x16x32_f16(pa1, b1, acco[dt], 0, 0, 0);
            acco[dt] = __builtin_amdgcn_mfma_f32_16x16x32_f16(pa2, b2, acco[dt], 0, 0, 0);
        }

        // ---- store O ----
        #pragma unroll
        for (int r = 0; r < 4; ++r) {
            const size_t grow = row0 + t * 64 + wave * 16 + quad * 4 + r;
            #pragma unroll
            for (int dt = 0; dt < 5; ++dt)
                oh[grow * EMBED + h * HEAD + dt * 16 + l16] =
                    (_Float16)(acco[dt][r] * recip[r]);
        }

        qa0 = qn0; qa1 = qn1; qa2 = qn2;
    }
}

// ---------------------------------------------------------------------------
extern "C" void kernel_launch(void* const* d_in, const int* in_sizes, int n_in,
                              void* d_out, int out_size, void* d_ws, size_t ws_size,
                              hipStream_t stream)
{
    const float* x  = (const float*)d_in[0];
    const float* y  = (const float*)d_in[1];
    const float* Wq = (const float*)d_in[2];
    const float* bq = (const float*)d_in[3];
    const float* Wk = (const float*)d_in[4];
    const float* bk = (const float*)d_in[5];
    const float* Wv = (const float*)d_in[6];
    const float* bv = (const float*)d_in[7];
    const float* Wo = (const float*)d_in[8];
    const float* bo = (const float*)d_in[9];
    float* out = (float*)d_out;

    const size_t ME = (size_t)MROWS * EMBED;
    _Float16* xh  = (_Float16*)d_ws;                          // [M][640]
    _Float16* qh  = xh + ME;                                  // [M][640]
    _Float16* ah  = qh + ME;                                  // [M][640]
    _Float16* kh  = ah + ME;                                  // [64][77][80]
    _Float16* vth = kh  + (size_t)BATCH * NH * SEQS * HEAD;   // [64][80][80]
    _Float16* wqt = vth + (size_t)BATCH * NH * HEAD * 80;     // [640][640]
    _Float16* wot = wqt + (size_t)EMBED * EMBED;              // [640][640]
    _Float16* yh  = wot + (size_t)EMBED * EMBED;              // [640][768]
    _Float16* wkt = yh  + (size_t)640 * CROSS;                // [640][768]
    _Float16* wvt = wkt + (size_t)EMBED * CROSS;              // [640][768]

    // prep
    cvt_f32_f16<<<dim3(ME / (256 * 8)), 256, 0, stream>>>(x, xh);
    transpose_cvt<<<dim3(EMBED / 32, EMBED / 32), dim3(32, 8), 0, stream>>>(Wq, wqt, EMBED, EMBED);
    transpose_cvt<<<dim3(EMBED / 32, EMBED / 32), dim3(32, 8), 0, stream>>>(Wo, wot, EMBED, EMBED);
    transpose_cvt<<<dim3(EMBED / 32, CROSS / 32), dim3(32, 8), 0, stream>>>(Wk, wkt, CROSS, EMBED);
    transpose_cvt<<<dim3(EMBED / 32, CROSS / 32), dim3(32, 8), 0, stream>>>(Wv, wvt, CROSS, EMBED);
    cvt_y_f16<<<dim3(640 * CROSS / (256 * 8)), 256, 0, stream>>>(y, yh);
    zero_f16<<<dim3(((size_t)BATCH * NH * HEAD * 80 / 8 + 255) / 256), 256, 0, stream>>>(
        vth, (size_t)BATCH * NH * HEAD * 80 / 8);

    // 1) Q = (x @ Wq + bq) * 1/sqrt(80), f16 out
    gemm_f16<true><<<dim3(EMBED / 128, MROWS / 128), 256, 0, stream>>>(
        xh, wqt, bq, qh, MROWS, EMBED, EMBED, 0.11180339887498949f);
    // 2) K,V projections via MFMA -> attention layouts
    kv_gemm<<<dim3(EMBED / 64, 640 / 64, 2), 256, 0, stream>>>(
        yh, wkt, wvt, bk, bv, kh, vth);
    // 3) MFMA attention: persistent K/V, 256 q-rows per block
    attn_mfma<<<dim3(SEQT / 256, BATCH * NH), 256, 0, stream>>>(qh, kh, vth, ah);
    // 4) out = attn_out @ Wo + bo (fp32 out)
    gemm_f16<false><<<dim3(EMBED / 128, MROWS / 128), 256, 0, stream>>>(
        ah, wot, bo, out, MROWS, EMBED, EMBED, 1.0f);
}